// Round 11
// baseline (210.491 us; speedup 1.0000x reference)
//
#include <hip/hip_runtime.h>

#define HIDDEN 16
#define CB 1024         // nodes per coarse bucket (power of two)
#define CB_SHIFT 10
#define NCB_MAX 512     // max coarse buckets
#define CHUNK 4096      // edges per block in hist/fill passes
#define SPL 8           // slice-blocks per bucket in count/scatter kernels
#define BT 1024         // threads per sliced block

// ======================= sorted-CSR path =======================

__global__ void k_zero0(unsigned int* cntc, int ncb,
                        unsigned int* rowptr, int n, unsigned int e) {
    int i = blockIdx.x * blockDim.x + threadIdx.x;
    if (i < ncb) cntc[i] = 0u;
    if (i == 0) rowptr[n] = e;   // sentinel
}

// per-chunk bucket histogram -> hcT[b*nchunk + chunk] (transposed) + totals
__global__ void k_hist_c(const int* __restrict__ dst, int e, int ncb, int nchunk,
                         unsigned int* __restrict__ cntc,
                         unsigned int* __restrict__ hcT) {
    __shared__ unsigned int h[NCB_MAX];
    for (int i = threadIdx.x; i < ncb; i += blockDim.x) h[i] = 0u;
    __syncthreads();
    int start = blockIdx.x * CHUNK;
    int end = min(start + CHUNK, e);
    int i = start + threadIdx.x;
    for (; i + 3 * 256 < end; i += 4 * 256) {
        unsigned d0 = dst[i], d1 = dst[i + 256], d2 = dst[i + 512], d3 = dst[i + 768];
        atomicAdd(&h[d0 >> CB_SHIFT], 1u);
        atomicAdd(&h[d1 >> CB_SHIFT], 1u);
        atomicAdd(&h[d2 >> CB_SHIFT], 1u);
        atomicAdd(&h[d3 >> CB_SHIFT], 1u);
    }
    for (; i < end; i += 256)
        atomicAdd(&h[((unsigned)dst[i]) >> CB_SHIFT], 1u);
    __syncthreads();
    for (int j = threadIdx.x; j < ncb; j += blockDim.x) {
        hcT[(size_t)j * nchunk + blockIdx.x] = h[j];
        if (h[j]) atomicAdd(&cntc[j], h[j]);
    }
}

// exclusive scan of bucket totals -> basec
__global__ void k_scan(const unsigned int* __restrict__ cnt, int nb,
                       unsigned int* __restrict__ base) {
    __shared__ unsigned int tsum[256];
    int t = threadIdx.x;
    int K = (nb + 255) / 256;
    unsigned int s = 0;
    for (int k = 0; k < K; k++) {
        int i = t * K + k;
        if (i < nb) s += cnt[i];
    }
    tsum[t] = s;
    __syncthreads();
    for (int off = 1; off < 256; off <<= 1) {
        unsigned int v = 0;
        if (t >= off) v = tsum[t - off];
        __syncthreads();
        if (t >= off) tsum[t] += v;
        __syncthreads();
    }
    unsigned int run = (t == 0) ? 0u : tsum[t - 1];
    for (int k = 0; k < K; k++) {
        int i = t * K + k;
        if (i < nb) { base[i] = run; run += cnt[i]; }
    }
}

// per-bucket scan over chunks: lbasec[b*nchunk + c] = basec[b] + prefix(hcT)
__global__ void k_scanc(const unsigned int* __restrict__ hcT,
                        const unsigned int* __restrict__ basec,
                        unsigned int* __restrict__ lbasec, int nchunk) {
    __shared__ unsigned int ts[256];
    __shared__ unsigned int carry;
    int b = blockIdx.x, t = threadIdx.x;
    if (t == 0) carry = basec[b];
    __syncthreads();
    for (int t0 = 0; t0 < nchunk; t0 += 256) {
        int i = t0 + t;
        unsigned int v = (i < nchunk) ? hcT[(size_t)b * nchunk + i] : 0u;
        ts[t] = v;
        __syncthreads();
        for (int off = 1; off < 256; off <<= 1) {
            unsigned int u = (t >= off) ? ts[t - off] : 0u;
            __syncthreads();
            ts[t] += u;
            __syncthreads();
        }
        if (i < nchunk) lbasec[(size_t)b * nchunk + i] = carry + ts[t] - v;
        __syncthreads();
        if (t == 0) carry += ts[255];
        __syncthreads();
    }
}

// scatter records (src<<10 | dst_local) using precomputed per-chunk bases
__global__ void k_fill_c(const int* __restrict__ src, const int* __restrict__ dst,
                         int e, int ncb, int nchunk,
                         const unsigned int* __restrict__ lbasec,
                         unsigned int* __restrict__ tmp) {
    __shared__ unsigned int h[NCB_MAX];
    __shared__ unsigned int lb[NCB_MAX];
    for (int j = threadIdx.x; j < ncb; j += blockDim.x) {
        lb[j] = lbasec[(size_t)j * nchunk + blockIdx.x];
        h[j] = 0u;
    }
    __syncthreads();
    int start = blockIdx.x * CHUNK;
    int end = min(start + CHUNK, e);
    for (int i = start + threadIdx.x; i < end; i += 256) {
        unsigned int d = (unsigned)dst[i];
        unsigned int s = (unsigned)src[i];
        unsigned int b = d >> CB_SHIFT;
        unsigned int r = atomicAdd(&h[b], 1u);
        tmp[lb[b] + r] = (s << CB_SHIFT) | (d & (CB - 1u));
    }
}

// per-slice per-node counts -> clsp[sl*n + node]
__global__ __launch_bounds__(BT) void
k_cls(const unsigned int* __restrict__ tmp,
      const unsigned int* __restrict__ basec,
      const unsigned int* __restrict__ cntc,
      unsigned int* __restrict__ clsp, int n) {
    __shared__ unsigned int degl[CB];
    int t = threadIdx.x;
    degl[t] = 0u;
    __syncthreads();
    int b = blockIdx.x / SPL, sl = blockIdx.x % SPL;
    unsigned int s = basec[b], m = cntc[b];
    for (unsigned int i = sl * BT + t; i < m; i += SPL * BT)
        atomicAdd(&degl[tmp[s + i] & (CB - 1u)], 1u);
    __syncthreads();
    int node = b * CB + t;
    if (node < n) clsp[(size_t)sl * n + node] = degl[t];
}

// per-bucket: deg, LDS scan -> rowptr, per-slice starts, fused inv+xs4 build
__global__ __launch_bounds__(BT) void
k_rowptr(const unsigned int* __restrict__ clsp,
         const unsigned int* __restrict__ basec,
         const float* __restrict__ x,
         unsigned int* __restrict__ rowptr, unsigned int* __restrict__ sstart,
         float4* __restrict__ xs4, int n) {
    __shared__ unsigned int sc[BT];
    int t = threadIdx.x;
    int b = blockIdx.x;
    int node = b * CB + t;
    unsigned int c[SPL];
    unsigned int d = 0;
    if (node < n) {
#pragma unroll
        for (int sl = 0; sl < SPL; sl++) {
            c[sl] = clsp[(size_t)sl * n + node];
            d += c[sl];
        }
    } else {
#pragma unroll
        for (int sl = 0; sl < SPL; sl++) c[sl] = 0u;
    }
    sc[t] = d;
    __syncthreads();
    for (int off = 1; off < BT; off <<= 1) {
        unsigned int v = (t >= off) ? sc[t - off] : 0u;
        __syncthreads();
        sc[t] += v;
        __syncthreads();
    }
    unsigned int rp = basec[b] + sc[t] - d;
    if (node <= n) rowptr[node] = rp;
    if (node < n) {
        unsigned int run = rp;
#pragma unroll
        for (int sl = 0; sl < SPL; sl++) {
            sstart[(size_t)sl * n + node] = run;
            run += c[sl];
        }
        float iv = rsqrtf((float)(1u + d));
        xs4[node] = make_float4(x[3 * node] * iv, x[3 * node + 1] * iv,
                                x[3 * node + 2] * iv, iv);
    }
}

// scatter src ids into dst-sorted tmp2
__global__ __launch_bounds__(BT) void
k_sortB(const unsigned int* __restrict__ tmp,
        const unsigned int* __restrict__ basec,
        const unsigned int* __restrict__ cntc,
        const unsigned int* __restrict__ sstart,
        unsigned int* __restrict__ tmp2, int n) {
    __shared__ unsigned int cur[CB];
    int t = threadIdx.x;
    int b = blockIdx.x / SPL, sl = blockIdx.x % SPL;
    int node = b * CB + t;
    cur[t] = (node < n) ? sstart[(size_t)sl * n + node] : 0u;
    __syncthreads();
    unsigned int s = basec[b], m = cntc[b];
    for (unsigned int i = sl * BT + t; i < m; i += SPL * BT) {
        unsigned int rec = tmp[s + i];
        unsigned int r = atomicAdd(&cur[rec & (CB - 1u)], 1u);
        tmp2[r] = rec >> CB_SHIFT;
    }
}

// layer-1: TWO threads per node (halves tail divergence, 2x gather MLP),
// pair-combine via shfl_xor, fused epilogue on even lane
__global__ void k_s1(const unsigned int* __restrict__ rowptr,
                     const unsigned int* __restrict__ tmp2,
                     const float4* __restrict__ xs4,
                     const float* __restrict__ W1, const float* __restrict__ b1,
                     const float* __restrict__ W2, const float* __restrict__ b2,
                     float* __restrict__ t2s, float* __restrict__ out, int n) {
    int gid = blockIdx.x * blockDim.x + threadIdx.x;
    int i = gid >> 1, h = gid & 1;
    bool valid = (i < n);
    unsigned int s = 0, epos = 0;
    if (valid) { s = rowptr[i]; epos = rowptr[i + 1]; }
    unsigned int half = (epos - s) >> 1;
    unsigned int b0 = h ? s + half : s;
    unsigned int b1r = h ? epos : s + half;
    float v0 = 0.f, v1 = 0.f, v2 = 0.f;
    unsigned int j = b0;
    for (; j + 4 <= b1r; j += 4) {
        unsigned a0 = tmp2[j], a1 = tmp2[j + 1], a2 = tmp2[j + 2], a3 = tmp2[j + 3];
        float4 p0 = xs4[a0], p1 = xs4[a1], p2 = xs4[a2], p3 = xs4[a3];
        v0 += (p0.x + p1.x) + (p2.x + p3.x);
        v1 += (p0.y + p1.y) + (p2.y + p3.y);
        v2 += (p0.z + p1.z) + (p2.z + p3.z);
    }
    for (; j < b1r; j++) {
        float4 p = xs4[tmp2[j]];
        v0 += p.x; v1 += p.y; v2 += p.z;
    }
    v0 += __shfl_xor(v0, 1);
    v1 += __shfl_xor(v1, 1);
    v2 += __shfl_xor(v2, 1);
    if (valid && h == 0) {
        float4 me = xs4[i];
        float iv = me.w;
        v0 = (v0 + me.x) * iv;       // + self-loop, × inv[dst]
        v1 = (v1 + me.y) * iv;
        v2 = (v2 + me.z) * iv;
        float acc = 0.f;
#pragma unroll
        for (int k = 0; k < HIDDEN; k++) {
            float hh = fmaxf(fmaf(v0, W1[k], fmaf(v1, W1[HIDDEN + k],
                            fmaf(v2, W1[2 * HIDDEN + k], b1[k]))), 0.f);
            acc += hh * W2[k];
        }
        t2s[i] = acc * iv;
        out[i] = b2[0] + acc * iv * iv;
    }
}

// layer-2: two threads per node, scalar gathers of t2s, pair-combine
__global__ void k_s2(const unsigned int* __restrict__ rowptr,
                     const unsigned int* __restrict__ tmp2,
                     const float* __restrict__ t2s, const float4* __restrict__ xs4,
                     float* __restrict__ out, int n) {
    int gid = blockIdx.x * blockDim.x + threadIdx.x;
    int i = gid >> 1, h = gid & 1;
    bool valid = (i < n);
    unsigned int s = 0, epos = 0;
    if (valid) { s = rowptr[i]; epos = rowptr[i + 1]; }
    unsigned int half = (epos - s) >> 1;
    unsigned int b0 = h ? s + half : s;
    unsigned int b1r = h ? epos : s + half;
    float v = 0.f;
    unsigned int j = b0;
    for (; j + 4 <= b1r; j += 4) {
        unsigned a0 = tmp2[j], a1 = tmp2[j + 1], a2 = tmp2[j + 2], a3 = tmp2[j + 3];
        v += (t2s[a0] + t2s[a1]) + (t2s[a2] + t2s[a3]);
    }
    for (; j < b1r; j++) v += t2s[tmp2[j]];
    v += __shfl_xor(v, 1);
    if (valid && h == 0) out[i] += v * xs4[i].w;
}

// ======================= split fallback backend =======================

__global__ void k_zero(unsigned int* a, int na) {
    int i = blockIdx.x * blockDim.x + threadIdx.x;
    if (i < na) a[i] = 0u;
}
__global__ __launch_bounds__(BT) void
k_deg_split(const unsigned int* __restrict__ tmp, const unsigned int* __restrict__ basec,
            const unsigned int* __restrict__ cntc, unsigned int* __restrict__ deg, int n) {
    __shared__ unsigned int degl[CB];
    int t = threadIdx.x;
    degl[t] = 0u;
    __syncthreads();
    int b = blockIdx.x / SPL, sl = blockIdx.x % SPL;
    unsigned int s = basec[b], m = cntc[b];
    for (unsigned int i = sl * BT + t; i < m; i += SPL * BT)
        atomicAdd(&degl[tmp[s + i] & (CB - 1u)], 1u);
    __syncthreads();
    int node = b * CB + t;
    unsigned int c = degl[t];
    if (node < n && c) atomicAdd(&deg[node], c);
}
__global__ void k_inv_s(const unsigned int* __restrict__ deg, const float* __restrict__ x,
                        float4* __restrict__ xs4, int n) {
    int i = blockIdx.x * blockDim.x + threadIdx.x;
    if (i >= n) return;
    float iv = rsqrtf((float)(deg[i] + 1u));
    xs4[i] = make_float4(x[3 * i] * iv, x[3 * i + 1] * iv, x[3 * i + 2] * iv, iv);
}
__global__ __launch_bounds__(BT) void
k_s1_split(const unsigned int* __restrict__ tmp, const unsigned int* __restrict__ basec,
           const unsigned int* __restrict__ cntc, const float4* __restrict__ xs4,
           float* __restrict__ agg0, float* __restrict__ agg1, float* __restrict__ agg2, int n) {
    __shared__ float a0[CB], a1[CB], a2[CB];
    int t = threadIdx.x;
    a0[t] = 0.f; a1[t] = 0.f; a2[t] = 0.f;
    __syncthreads();
    int b = blockIdx.x / SPL, sl = blockIdx.x % SPL;
    unsigned int s = basec[b], m = cntc[b];
    for (unsigned int i = sl * BT + t; i < m; i += SPL * BT) {
        unsigned rec = tmp[s + i];
        float4 v = xs4[rec >> CB_SHIFT];
        unsigned dl = rec & (CB - 1u);
        atomicAdd(&a0[dl], v.x); atomicAdd(&a1[dl], v.y); atomicAdd(&a2[dl], v.z);
    }
    __syncthreads();
    int node = b * CB + t;
    if (node < n) {
        if (a0[t] != 0.f) atomicAdd(&agg0[node], a0[t]);
        if (a1[t] != 0.f) atomicAdd(&agg1[node], a1[t]);
        if (a2[t] != 0.f) atomicAdd(&agg2[node], a2[t]);
    }
}
__global__ void k_epi_s(const float* __restrict__ agg0, const float* __restrict__ agg1,
                        const float* __restrict__ agg2, const float4* __restrict__ xs4,
                        const float* __restrict__ W1, const float* __restrict__ b1,
                        const float* __restrict__ W2, const float* __restrict__ b2,
                        float* __restrict__ t2s, float* __restrict__ out, int n) {
    int i = blockIdx.x * blockDim.x + threadIdx.x;
    if (i >= n) return;
    float4 xv = xs4[i];
    float iv = xv.w;
    float v0 = iv * (agg0[i] + xv.x), v1 = iv * (agg1[i] + xv.y), v2 = iv * (agg2[i] + xv.z);
    float acc = 0.f;
#pragma unroll
    for (int j = 0; j < HIDDEN; j++) {
        float h = fmaxf(fmaf(v0, W1[j], fmaf(v1, W1[HIDDEN + j],
                       fmaf(v2, W1[2 * HIDDEN + j], b1[j]))), 0.f);
        acc += h * W2[j];
    }
    t2s[i] = acc * iv;
    out[i] = b2[0] + acc * iv * iv;
}
__global__ __launch_bounds__(BT) void
k_s2_split(const unsigned int* __restrict__ tmp, const unsigned int* __restrict__ basec,
           const unsigned int* __restrict__ cntc, const float* __restrict__ t2s,
           const float4* __restrict__ xs4, float* __restrict__ out, int n) {
    __shared__ float o[CB];
    int t = threadIdx.x;
    o[t] = 0.f;
    __syncthreads();
    int b = blockIdx.x / SPL, sl = blockIdx.x % SPL;
    unsigned int s = basec[b], m = cntc[b];
    for (unsigned int i = sl * BT + t; i < m; i += SPL * BT) {
        unsigned rec = tmp[s + i];
        atomicAdd(&o[rec & (CB - 1u)], t2s[rec >> CB_SHIFT]);
    }
    __syncthreads();
    int node = b * CB + t;
    if (node < n && o[t] != 0.f) atomicAdd(&out[node], o[t] * xs4[node].w);
}

// ======================= launch =======================

extern "C" void kernel_launch(void* const* d_in, const int* in_sizes, int n_in,
                              void* d_out, int out_size, void* d_ws, size_t ws_size,
                              hipStream_t stream) {
    const float* x  = (const float*)d_in[0];
    const int*   ei = (const int*)d_in[1];
    const float* W1 = (const float*)d_in[2];
    const float* b1 = (const float*)d_in[3];
    const float* W2 = (const float*)d_in[4];
    const float* b2 = (const float*)d_in[5];
    float* out = (float*)d_out;

    int n = in_sizes[0] / 3;
    int e = in_sizes[1] / 2;
    const int* src = ei;
    const int* dst = ei + e;
    const int B = 256;

    int ncb = (n + CB - 1) / CB;
    int gridE = (e + CHUNK - 1) / CHUNK;
    int gridN = (n + B - 1) / B;
    int gridN2 = (2 * n + B - 1) / B;

    size_t needcsr = (size_t)n * 16 + (size_t)n * 4 + (size_t)(n + 1) * 4
                   + (size_t)SPL * n * 8 + (size_t)ncb * 8
                   + (size_t)ncb * gridE * 8 + (size_t)e * 8 + 64;
    size_t needsp = (size_t)n * 16 + (size_t)n * 16 + (size_t)n * 4
                  + (size_t)ncb * 8 + (size_t)ncb * gridE * 8 + (size_t)e * 4;

    if (ncb <= NCB_MAX && n < (1 << 21) && ws_size >= needcsr) {
        float4* xs4 = (float4*)d_ws;                            // n
        float* t2s = (float*)(xs4 + n);                         // n
        unsigned int* rowptr = (unsigned int*)(t2s + n);        // n+1
        unsigned int* clsp   = rowptr + (n + 1);                // SPL*n
        unsigned int* sstart = clsp + (size_t)SPL * n;          // SPL*n
        unsigned int* cntc   = sstart + (size_t)SPL * n;        // ncb
        unsigned int* basec  = cntc + ncb;                      // ncb
        unsigned int* hcT    = basec + ncb;                     // ncb*gridE
        unsigned int* lbasec = hcT + (size_t)ncb * gridE;       // ncb*gridE
        unsigned int* tmp    = lbasec + (size_t)ncb * gridE;    // e
        unsigned int* tmp2   = tmp + e;                         // e

        k_zero0<<<(ncb + B - 1) / B, B, 0, stream>>>(cntc, ncb, rowptr, n, (unsigned)e);
        k_hist_c<<<gridE, B, 0, stream>>>(dst, e, ncb, gridE, cntc, hcT);
        k_scan<<<1, B, 0, stream>>>(cntc, ncb, basec);
        k_scanc<<<ncb, B, 0, stream>>>(hcT, basec, lbasec, gridE);
        k_fill_c<<<gridE, B, 0, stream>>>(src, dst, e, ncb, gridE, lbasec, tmp);
        k_cls<<<ncb * SPL, BT, 0, stream>>>(tmp, basec, cntc, clsp, n);
        k_rowptr<<<ncb, BT, 0, stream>>>(clsp, basec, x, rowptr, sstart, xs4, n);
        k_sortB<<<ncb * SPL, BT, 0, stream>>>(tmp, basec, cntc, sstart, tmp2, n);
        k_s1<<<gridN2, B, 0, stream>>>(rowptr, tmp2, xs4, W1, b1, W2, b2, t2s, out, n);
        k_s2<<<gridN2, B, 0, stream>>>(rowptr, tmp2, t2s, xs4, out, n);
    } else if (ncb <= NCB_MAX && n < (1 << 22) && ws_size >= needsp) {
        float4* xs4 = (float4*)d_ws;
        float* agg0 = (float*)(xs4 + n);
        float* agg1 = agg0 + n;
        float* agg2 = agg1 + n;
        unsigned int* deg = (unsigned int*)(agg2 + n);
        float* t2s = (float*)(deg + n);
        unsigned int* cntc   = (unsigned int*)(t2s + n);
        unsigned int* basec  = cntc + ncb;
        unsigned int* hcT    = basec + ncb;
        unsigned int* lbasec = hcT + (size_t)ncb * gridE;
        unsigned int* tmp    = lbasec + (size_t)ncb * gridE;

        k_zero<<<(4 * n + ncb + B - 1) / B, B, 0, stream>>>((unsigned int*)agg0, 4 * n);
        k_zero<<<(ncb + B - 1) / B, B, 0, stream>>>(cntc, ncb);
        k_hist_c<<<gridE, B, 0, stream>>>(dst, e, ncb, gridE, cntc, hcT);
        k_scan<<<1, B, 0, stream>>>(cntc, ncb, basec);
        k_scanc<<<ncb, B, 0, stream>>>(hcT, basec, lbasec, gridE);
        k_fill_c<<<gridE, B, 0, stream>>>(src, dst, e, ncb, gridE, lbasec, tmp);
        k_deg_split<<<ncb * SPL, BT, 0, stream>>>(tmp, basec, cntc, deg, n);
        k_inv_s<<<gridN, B, 0, stream>>>(deg, x, xs4, n);
        k_s1_split<<<ncb * SPL, BT, 0, stream>>>(tmp, basec, cntc, xs4, agg0, agg1, agg2, n);
        k_epi_s<<<gridN, B, 0, stream>>>(agg0, agg1, agg2, xs4, W1, b1, W2, b2, t2s, out, n);
        k_s2_split<<<ncb * SPL, BT, 0, stream>>>(tmp, basec, cntc, t2s, xs4, out, n);
    }
}

// Round 12
// 190.275 us; speedup vs baseline: 1.1062x; 1.1062x over previous
//
#include <hip/hip_runtime.h>

#define HIDDEN 16
// ---- fine-bucket sorted-CSR path ----
#define FB 128          // nodes per fine bucket (power of two)
#define FB_SHIFT 7
#define NBK_MAX 4096    // LDS limit for hist/fill (n <= 524288)
#define FCHUNK 8192     // edges per block in hist/fill
#define FTH 512         // threads in hist/fill blocks
// ---- fallback (split) path ----
#define CB 1024
#define CB_SHIFT 10
#define NCB_MAX 512
#define CHUNK 4096
#define SPL 8
#define BT 1024

// ======================= fine-bucket path =======================

// per-chunk per-bucket histogram -> hcT[bucket*nchunk + chunk]
__global__ __launch_bounds__(FTH) void
k_histf(const int* __restrict__ dst, int e, int nbk, int nchunk,
        unsigned int* __restrict__ hcT) {
    __shared__ unsigned int h[NBK_MAX];   // 16 KB
    for (int i = threadIdx.x; i < nbk; i += FTH) h[i] = 0u;
    __syncthreads();
    int start = blockIdx.x * FCHUNK;
    int end = min(start + FCHUNK, e);
    for (int i = start + threadIdx.x; i < end; i += FTH)
        atomicAdd(&h[((unsigned)dst[i]) >> FB_SHIFT], 1u);
    __syncthreads();
    for (int j = threadIdx.x; j < nbk; j += FTH)
        hcT[(size_t)j * nchunk + blockIdx.x] = h[j];   // 1.2 MB total, L2-absorbed
}

// block per bucket: in-place exclusive scan of hcT row -> relative bases; total -> cntc
__global__ void k_scanf(unsigned int* __restrict__ hcT,
                        unsigned int* __restrict__ cntc, int nchunk) {
    __shared__ unsigned int ts[256];
    __shared__ unsigned int carry;
    int b = blockIdx.x, t = threadIdx.x;
    if (t == 0) carry = 0u;
    __syncthreads();
    size_t row = (size_t)b * nchunk;
    for (int t0 = 0; t0 < nchunk; t0 += 256) {
        int i = t0 + t;
        unsigned int v = (i < nchunk) ? hcT[row + i] : 0u;
        ts[t] = v;
        __syncthreads();
        for (int off = 1; off < 256; off <<= 1) {
            unsigned int u = (t >= off) ? ts[t - off] : 0u;
            __syncthreads();
            ts[t] += u;
            __syncthreads();
        }
        if (i < nchunk) hcT[row + i] = carry + ts[t] - v;
        __syncthreads();
        if (t == 0) carry += ts[255];
        __syncthreads();
    }
    if (t == 0) cntc[b] = carry;
}

// exclusive scan of bucket totals -> basec (+ sentinels)
__global__ __launch_bounds__(1024) void
k_scanb(const unsigned int* __restrict__ cntc, int nbk,
        unsigned int* __restrict__ basec,
        unsigned int* __restrict__ rowptr, int n, unsigned int e) {
    __shared__ unsigned int tsum[1024];
    int t = threadIdx.x;
    int K = (nbk + 1023) / 1024;
    unsigned int s = 0;
    for (int k = 0; k < K; k++) {
        int i = t * K + k;
        if (i < nbk) s += cntc[i];
    }
    tsum[t] = s;
    __syncthreads();
    for (int off = 1; off < 1024; off <<= 1) {
        unsigned int v = (t >= off) ? tsum[t - off] : 0u;
        __syncthreads();
        tsum[t] += v;
        __syncthreads();
    }
    unsigned int run = (t == 0) ? 0u : tsum[t - 1];
    for (int k = 0; k < K; k++) {
        int i = t * K + k;
        if (i < nbk) { basec[i] = run; run += cntc[i]; }
    }
    if (t == 1023) basec[nbk] = tsum[1023];  // == e
    if (t == 0) rowptr[n] = e;               // CSR sentinel
}

// scatter records (src<<7 | dst&127) using precomputed bases; no cursor atomics
__global__ __launch_bounds__(FTH) void
k_fillf(const int* __restrict__ src, const int* __restrict__ dst,
        int e, int nbk, int nchunk,
        const unsigned int* __restrict__ basec,
        const unsigned int* __restrict__ hcT,
        unsigned int* __restrict__ tmp) {
    __shared__ unsigned int h[NBK_MAX];    // 16 KB
    __shared__ unsigned int lb[NBK_MAX];   // 16 KB
    for (int j = threadIdx.x; j < nbk; j += FTH) {
        lb[j] = basec[j] + hcT[(size_t)j * nchunk + blockIdx.x];
        h[j] = 0u;
    }
    __syncthreads();
    int start = blockIdx.x * FCHUNK;
    int end = min(start + FCHUNK, e);
    for (int i = start + threadIdx.x; i < end; i += FTH) {
        unsigned int d = (unsigned)dst[i];
        unsigned int s = (unsigned)src[i];
        unsigned int b = d >> FB_SHIFT;
        unsigned int r = atomicAdd(&h[b], 1u);
        tmp[lb[b] + r] = (s << FB_SHIFT) | (d & (FB - 1u));
    }
}

// FUSED per-bucket counting sort: count -> scan -> rowptr+xs4 -> scatter.
// One 256-thread block per 128-node bucket; segment ~16 KB stays L2-hot
// between the two passes. Replaces k_cls + k_rowptr + k_sortB.
__global__ __launch_bounds__(256) void
k_sortN(const unsigned int* __restrict__ tmp,
        const unsigned int* __restrict__ basec,
        const float* __restrict__ x,
        unsigned int* __restrict__ rowptr, unsigned int* __restrict__ tmp2,
        float4* __restrict__ xs4, int n) {
    __shared__ unsigned int cnt[FB];
    __shared__ unsigned int sc[FB];
    __shared__ unsigned int cur[FB];
    int t = threadIdx.x, b = blockIdx.x;
    unsigned int s = basec[b], endp = basec[b + 1];
    if (t < FB) cnt[t] = 0u;
    __syncthreads();
    for (unsigned int i = s + t; i < endp; i += 256)       // pass A: count
        atomicAdd(&cnt[tmp[i] & (FB - 1u)], 1u);
    __syncthreads();
    if (t < FB) sc[t] = cnt[t];
    __syncthreads();
    for (int off = 1; off < FB; off <<= 1) {               // inclusive scan
        unsigned int v = (t < FB && t >= off) ? sc[t - off] : 0u;
        __syncthreads();
        if (t < FB && t >= off) sc[t] += v;
        __syncthreads();
    }
    if (t < FB) {
        unsigned int excl = sc[t] - cnt[t];
        cur[t] = s + excl;
        int node = (b << FB_SHIFT) + t;
        if (node < n) {
            rowptr[node] = s + excl;
            float iv = rsqrtf((float)(1u + cnt[t]));       // +1 self-loop
            xs4[node] = make_float4(x[3 * node] * iv, x[3 * node + 1] * iv,
                                    x[3 * node + 2] * iv, iv);
        }
    }
    __syncthreads();
    for (unsigned int i = s + t; i < endp; i += 256) {     // pass B: scatter
        unsigned int rec = tmp[i];                         // L2-hot re-read
        unsigned int r = atomicAdd(&cur[rec & (FB - 1u)], 1u);
        tmp2[r] = rec >> FB_SHIFT;                         // src id
    }
}

// layer-1: two threads per node, pair-combine via shfl_xor, fused epilogue
__global__ void k_s1(const unsigned int* __restrict__ rowptr,
                     const unsigned int* __restrict__ tmp2,
                     const float4* __restrict__ xs4,
                     const float* __restrict__ W1, const float* __restrict__ b1,
                     const float* __restrict__ W2, const float* __restrict__ b2,
                     float* __restrict__ t2s, float* __restrict__ out, int n) {
    int gid = blockIdx.x * blockDim.x + threadIdx.x;
    int i = gid >> 1, h = gid & 1;
    bool valid = (i < n);
    unsigned int s = 0, epos = 0;
    if (valid) { s = rowptr[i]; epos = rowptr[i + 1]; }
    unsigned int half = (epos - s) >> 1;
    unsigned int b0 = h ? s + half : s;
    unsigned int b1r = h ? epos : s + half;
    float v0 = 0.f, v1 = 0.f, v2 = 0.f;
    unsigned int j = b0;
    for (; j + 4 <= b1r; j += 4) {
        unsigned a0 = tmp2[j], a1 = tmp2[j + 1], a2 = tmp2[j + 2], a3 = tmp2[j + 3];
        float4 p0 = xs4[a0], p1 = xs4[a1], p2 = xs4[a2], p3 = xs4[a3];
        v0 += (p0.x + p1.x) + (p2.x + p3.x);
        v1 += (p0.y + p1.y) + (p2.y + p3.y);
        v2 += (p0.z + p1.z) + (p2.z + p3.z);
    }
    for (; j < b1r; j++) {
        float4 p = xs4[tmp2[j]];
        v0 += p.x; v1 += p.y; v2 += p.z;
    }
    v0 += __shfl_xor(v0, 1);
    v1 += __shfl_xor(v1, 1);
    v2 += __shfl_xor(v2, 1);
    if (valid && h == 0) {
        float4 me = xs4[i];
        float iv = me.w;
        v0 = (v0 + me.x) * iv;
        v1 = (v1 + me.y) * iv;
        v2 = (v2 + me.z) * iv;
        float acc = 0.f;
#pragma unroll
        for (int k = 0; k < HIDDEN; k++) {
            float hh = fmaxf(fmaf(v0, W1[k], fmaf(v1, W1[HIDDEN + k],
                            fmaf(v2, W1[2 * HIDDEN + k], b1[k]))), 0.f);
            acc += hh * W2[k];
        }
        t2s[i] = acc * iv;
        out[i] = b2[0] + acc * iv * iv;
    }
}

// layer-2: two threads per node, scalar gathers of t2s, pair-combine
__global__ void k_s2(const unsigned int* __restrict__ rowptr,
                     const unsigned int* __restrict__ tmp2,
                     const float* __restrict__ t2s, const float4* __restrict__ xs4,
                     float* __restrict__ out, int n) {
    int gid = blockIdx.x * blockDim.x + threadIdx.x;
    int i = gid >> 1, h = gid & 1;
    bool valid = (i < n);
    unsigned int s = 0, epos = 0;
    if (valid) { s = rowptr[i]; epos = rowptr[i + 1]; }
    unsigned int half = (epos - s) >> 1;
    unsigned int b0 = h ? s + half : s;
    unsigned int b1r = h ? epos : s + half;
    float v = 0.f;
    unsigned int j = b0;
    for (; j + 4 <= b1r; j += 4) {
        unsigned a0 = tmp2[j], a1 = tmp2[j + 1], a2 = tmp2[j + 2], a3 = tmp2[j + 3];
        v += (t2s[a0] + t2s[a1]) + (t2s[a2] + t2s[a3]);
    }
    for (; j < b1r; j++) v += t2s[tmp2[j]];
    v += __shfl_xor(v, 1);
    if (valid && h == 0) out[i] += v * xs4[i].w;
}

// ======================= split fallback backend =======================

__global__ void k_zero(unsigned int* a, int na) {
    int i = blockIdx.x * blockDim.x + threadIdx.x;
    if (i < na) a[i] = 0u;
}
__global__ void k_hist_c(const int* __restrict__ dst, int e, int ncb, int nchunk,
                         unsigned int* __restrict__ cntc,
                         unsigned int* __restrict__ hcT) {
    __shared__ unsigned int h[NCB_MAX];
    for (int i = threadIdx.x; i < ncb; i += blockDim.x) h[i] = 0u;
    __syncthreads();
    int start = blockIdx.x * CHUNK;
    int end = min(start + CHUNK, e);
    for (int i = start + threadIdx.x; i < end; i += 256)
        atomicAdd(&h[((unsigned)dst[i]) >> CB_SHIFT], 1u);
    __syncthreads();
    for (int j = threadIdx.x; j < ncb; j += blockDim.x) {
        hcT[(size_t)j * nchunk + blockIdx.x] = h[j];
        if (h[j]) atomicAdd(&cntc[j], h[j]);
    }
}
__global__ void k_scan(const unsigned int* __restrict__ cnt, int nb,
                       unsigned int* __restrict__ base) {
    __shared__ unsigned int tsum[256];
    int t = threadIdx.x;
    int K = (nb + 255) / 256;
    unsigned int s = 0;
    for (int k = 0; k < K; k++) {
        int i = t * K + k;
        if (i < nb) s += cnt[i];
    }
    tsum[t] = s;
    __syncthreads();
    for (int off = 1; off < 256; off <<= 1) {
        unsigned int v = (t >= off) ? tsum[t - off] : 0u;
        __syncthreads();
        tsum[t] += v;
        __syncthreads();
    }
    unsigned int run = (t == 0) ? 0u : tsum[t - 1];
    for (int k = 0; k < K; k++) {
        int i = t * K + k;
        if (i < nb) { base[i] = run; run += cnt[i]; }
    }
}
__global__ void k_scanc(const unsigned int* __restrict__ hcT,
                        const unsigned int* __restrict__ basec,
                        unsigned int* __restrict__ lbasec, int nchunk) {
    __shared__ unsigned int ts[256];
    __shared__ unsigned int carry;
    int b = blockIdx.x, t = threadIdx.x;
    if (t == 0) carry = basec[b];
    __syncthreads();
    for (int t0 = 0; t0 < nchunk; t0 += 256) {
        int i = t0 + t;
        unsigned int v = (i < nchunk) ? hcT[(size_t)b * nchunk + i] : 0u;
        ts[t] = v;
        __syncthreads();
        for (int off = 1; off < 256; off <<= 1) {
            unsigned int u = (t >= off) ? ts[t - off] : 0u;
            __syncthreads();
            ts[t] += u;
            __syncthreads();
        }
        if (i < nchunk) lbasec[(size_t)b * nchunk + i] = carry + ts[t] - v;
        __syncthreads();
        if (t == 0) carry += ts[255];
        __syncthreads();
    }
}
__global__ void k_fill_c(const int* __restrict__ src, const int* __restrict__ dst,
                         int e, int ncb, int nchunk,
                         const unsigned int* __restrict__ lbasec,
                         unsigned int* __restrict__ tmp) {
    __shared__ unsigned int h[NCB_MAX];
    __shared__ unsigned int lb[NCB_MAX];
    for (int j = threadIdx.x; j < ncb; j += blockDim.x) {
        lb[j] = lbasec[(size_t)j * nchunk + blockIdx.x];
        h[j] = 0u;
    }
    __syncthreads();
    int start = blockIdx.x * CHUNK;
    int end = min(start + CHUNK, e);
    for (int i = start + threadIdx.x; i < end; i += 256) {
        unsigned int d = (unsigned)dst[i];
        unsigned int b = d >> CB_SHIFT;
        unsigned int r = atomicAdd(&h[b], 1u);
        tmp[lb[b] + r] = (((unsigned)src[i]) << CB_SHIFT) | (d & (CB - 1u));
    }
}
__global__ __launch_bounds__(BT) void
k_deg_split(const unsigned int* __restrict__ tmp, const unsigned int* __restrict__ basec,
            const unsigned int* __restrict__ cntc, unsigned int* __restrict__ deg, int n) {
    __shared__ unsigned int degl[CB];
    int t = threadIdx.x;
    degl[t] = 0u;
    __syncthreads();
    int b = blockIdx.x / SPL, sl = blockIdx.x % SPL;
    unsigned int s = basec[b], m = cntc[b];
    for (unsigned int i = sl * BT + t; i < m; i += SPL * BT)
        atomicAdd(&degl[tmp[s + i] & (CB - 1u)], 1u);
    __syncthreads();
    int node = b * CB + t;
    unsigned int c = degl[t];
    if (node < n && c) atomicAdd(&deg[node], c);
}
__global__ void k_inv_s(const unsigned int* __restrict__ deg, const float* __restrict__ x,
                        float4* __restrict__ xs4, int n) {
    int i = blockIdx.x * blockDim.x + threadIdx.x;
    if (i >= n) return;
    float iv = rsqrtf((float)(deg[i] + 1u));
    xs4[i] = make_float4(x[3 * i] * iv, x[3 * i + 1] * iv, x[3 * i + 2] * iv, iv);
}
__global__ __launch_bounds__(BT) void
k_s1_split(const unsigned int* __restrict__ tmp, const unsigned int* __restrict__ basec,
           const unsigned int* __restrict__ cntc, const float4* __restrict__ xs4,
           float* __restrict__ agg0, float* __restrict__ agg1, float* __restrict__ agg2, int n) {
    __shared__ float a0[CB], a1[CB], a2[CB];
    int t = threadIdx.x;
    a0[t] = 0.f; a1[t] = 0.f; a2[t] = 0.f;
    __syncthreads();
    int b = blockIdx.x / SPL, sl = blockIdx.x % SPL;
    unsigned int s = basec[b], m = cntc[b];
    for (unsigned int i = sl * BT + t; i < m; i += SPL * BT) {
        unsigned rec = tmp[s + i];
        float4 v = xs4[rec >> CB_SHIFT];
        unsigned dl = rec & (CB - 1u);
        atomicAdd(&a0[dl], v.x); atomicAdd(&a1[dl], v.y); atomicAdd(&a2[dl], v.z);
    }
    __syncthreads();
    int node = b * CB + t;
    if (node < n) {
        if (a0[t] != 0.f) atomicAdd(&agg0[node], a0[t]);
        if (a1[t] != 0.f) atomicAdd(&agg1[node], a1[t]);
        if (a2[t] != 0.f) atomicAdd(&agg2[node], a2[t]);
    }
}
__global__ void k_epi_s(const float* __restrict__ agg0, const float* __restrict__ agg1,
                        const float* __restrict__ agg2, const float4* __restrict__ xs4,
                        const float* __restrict__ W1, const float* __restrict__ b1,
                        const float* __restrict__ W2, const float* __restrict__ b2,
                        float* __restrict__ t2s, float* __restrict__ out, int n) {
    int i = blockIdx.x * blockDim.x + threadIdx.x;
    if (i >= n) return;
    float4 xv = xs4[i];
    float iv = xv.w;
    float v0 = iv * (agg0[i] + xv.x), v1 = iv * (agg1[i] + xv.y), v2 = iv * (agg2[i] + xv.z);
    float acc = 0.f;
#pragma unroll
    for (int j = 0; j < HIDDEN; j++) {
        float h = fmaxf(fmaf(v0, W1[j], fmaf(v1, W1[HIDDEN + j],
                       fmaf(v2, W1[2 * HIDDEN + j], b1[j]))), 0.f);
        acc += h * W2[j];
    }
    t2s[i] = acc * iv;
    out[i] = b2[0] + acc * iv * iv;
}
__global__ __launch_bounds__(BT) void
k_s2_split(const unsigned int* __restrict__ tmp, const unsigned int* __restrict__ basec,
           const unsigned int* __restrict__ cntc, const float* __restrict__ t2s,
           const float4* __restrict__ xs4, float* __restrict__ out, int n) {
    __shared__ float o[CB];
    int t = threadIdx.x;
    o[t] = 0.f;
    __syncthreads();
    int b = blockIdx.x / SPL, sl = blockIdx.x % SPL;
    unsigned int s = basec[b], m = cntc[b];
    for (unsigned int i = sl * BT + t; i < m; i += SPL * BT) {
        unsigned rec = tmp[s + i];
        atomicAdd(&o[rec & (CB - 1u)], t2s[rec >> CB_SHIFT]);
    }
    __syncthreads();
    int node = b * CB + t;
    if (node < n && o[t] != 0.f) atomicAdd(&out[node], o[t] * xs4[node].w);
}

// ======================= launch =======================

extern "C" void kernel_launch(void* const* d_in, const int* in_sizes, int n_in,
                              void* d_out, int out_size, void* d_ws, size_t ws_size,
                              hipStream_t stream) {
    const float* x  = (const float*)d_in[0];
    const int*   ei = (const int*)d_in[1];
    const float* W1 = (const float*)d_in[2];
    const float* b1 = (const float*)d_in[3];
    const float* W2 = (const float*)d_in[4];
    const float* b2 = (const float*)d_in[5];
    float* out = (float*)d_out;

    int n = in_sizes[0] / 3;
    int e = in_sizes[1] / 2;
    const int* src = ei;
    const int* dst = ei + e;
    const int B = 256;

    int nbk = (n + FB - 1) / FB;
    int nchunkf = (e + FCHUNK - 1) / FCHUNK;
    int gridN2 = (2 * n + B - 1) / B;

    // fine path ws: xs4[n] | t2s[n] | rowptr[n+1] | cntc[nbk] basec[nbk+1]
    //             | hcT[nbk*nchunkf] | tmp[e] | tmp2[e]
    size_t needf = (size_t)n * 16 + (size_t)n * 4 + (size_t)(n + 1) * 4
                 + (size_t)(2 * nbk + 1) * 4 + (size_t)nbk * nchunkf * 4
                 + (size_t)e * 8 + 64;

    if (nbk <= NBK_MAX && n < (1 << 25) && ws_size >= needf) {
        float4* xs4 = (float4*)d_ws;                            // n
        float* t2s = (float*)(xs4 + n);                         // n
        unsigned int* rowptr = (unsigned int*)(t2s + n);        // n+1
        unsigned int* cntc   = rowptr + (n + 1);                // nbk
        unsigned int* basec  = cntc + nbk;                      // nbk+1
        unsigned int* hcT    = basec + nbk + 1;                 // nbk*nchunkf
        unsigned int* tmp    = hcT + (size_t)nbk * nchunkf;     // e
        unsigned int* tmp2   = tmp + e;                         // e

        k_histf<<<nchunkf, FTH, 0, stream>>>(dst, e, nbk, nchunkf, hcT);
        k_scanf<<<nbk, 256, 0, stream>>>(hcT, cntc, nchunkf);
        k_scanb<<<1, 1024, 0, stream>>>(cntc, nbk, basec, rowptr, n, (unsigned)e);
        k_fillf<<<nchunkf, FTH, 0, stream>>>(src, dst, e, nbk, nchunkf, basec, hcT, tmp);
        k_sortN<<<nbk, 256, 0, stream>>>(tmp, basec, x, rowptr, tmp2, xs4, n);
        k_s1<<<gridN2, B, 0, stream>>>(rowptr, tmp2, xs4, W1, b1, W2, b2, t2s, out, n);
        k_s2<<<gridN2, B, 0, stream>>>(rowptr, tmp2, t2s, xs4, out, n);
    } else {
        int ncb = (n + CB - 1) / CB;
        int gridE = (e + CHUNK - 1) / CHUNK;
        int gridN = (n + B - 1) / B;
        float4* xs4 = (float4*)d_ws;
        float* agg0 = (float*)(xs4 + n);
        float* agg1 = agg0 + n;
        float* agg2 = agg1 + n;
        unsigned int* deg = (unsigned int*)(agg2 + n);
        float* t2s = (float*)(deg + n);
        unsigned int* cntc   = (unsigned int*)(t2s + n);
        unsigned int* basec  = cntc + ncb;
        unsigned int* hcT    = basec + ncb;
        unsigned int* lbasec = hcT + (size_t)ncb * gridE;
        unsigned int* tmp    = lbasec + (size_t)ncb * gridE;

        k_zero<<<(4 * n + ncb + B - 1) / B, B, 0, stream>>>((unsigned int*)agg0, 4 * n);
        k_zero<<<(ncb + B - 1) / B, B, 0, stream>>>(cntc, ncb);
        k_hist_c<<<gridE, B, 0, stream>>>(dst, e, ncb, gridE, cntc, hcT);
        k_scan<<<1, B, 0, stream>>>(cntc, ncb, basec);
        k_scanc<<<ncb, B, 0, stream>>>(hcT, basec, lbasec, gridE);
        k_fill_c<<<gridE, B, 0, stream>>>(src, dst, e, ncb, gridE, lbasec, tmp);
        k_deg_split<<<ncb * SPL, BT, 0, stream>>>(tmp, basec, cntc, deg, n);
        k_inv_s<<<gridN, B, 0, stream>>>(deg, x, xs4, n);
        k_s1_split<<<ncb * SPL, BT, 0, stream>>>(tmp, basec, cntc, xs4, agg0, agg1, agg2, n);
        k_epi_s<<<gridN, B, 0, stream>>>(agg0, agg1, agg2, xs4, W1, b1, W2, b2, t2s, out, n);
        k_s2_split<<<ncb * SPL, BT, 0, stream>>>(tmp, basec, cntc, t2s, xs4, out, n);
    }
}